// Round 7
// baseline (520.878 us; speedup 1.0000x reference)
//
#include <hip/hip_runtime.h>
#include <hip/hip_bf16.h>

// MSDNet on MI355X. Only scale 2's chain matters (scales 0/1 are dead code),
// and final_logits == logits at depth 3.
// Pipeline:
//   conv_init (fp32 VALU, cin=3) -> bf16 NHWC feats
//   4x conv_mfma (bf16 MFMA implicit GEMM, 128->128), BARRIER-FREE K-loop:
//     A (input patch) staged once in LDS; B (weights) pre-shuffled to
//     FRAGMENT-MAJOR layout so each wave's B-fragment is one coalesced 1KB
//     global load (L2-resident), depth-2 register pipeline. No weight LDS,
//     no K-loop barriers, 3 blocks/CU. Fused f32 pooling in epilogue;
//     layer 3 skips feature stores (dead output).
//   logits_k ; select_k (early-exit)

typedef unsigned int uint;
typedef unsigned short u16;
typedef __bf16 bf16x8 __attribute__((ext_vector_type(8)));
typedef short short8 __attribute__((ext_vector_type(8)));
typedef unsigned short ushort8 __attribute__((ext_vector_type(8)));
typedef float f32x4 __attribute__((ext_vector_type(4)));

#define NB   16
#define CCH  128
#define NCLS 100
#define HW   12544      // 112*112
#define NTILE 98        // 14 h-tiles x 7 w-tiles per image

__device__ __forceinline__ u16 f2bf(float f) {
    uint u = __float_as_uint(f);
    return (u16)((u + 0x7fffu + ((u >> 16) & 1u)) >> 16);
}

// ---------------- weight convert to FRAGMENT-MAJOR bf16 ----------------
// wb[d][s][wn][nj][lane][e]  (s = tap*4 + q, cout = wn*64+nj*16+(lane&15),
//                            cin = q*32 + (lane>>4)*8 + e)
// One wave fragment = 64 lanes x 16B contiguous = 1KB coalesced load.
__global__ __launch_bounds__(256) void convert_w(
    const float* __restrict__ bw, u16* __restrict__ wb)
{
    int idx = blockIdx.x * 256 + threadIdx.x;        // 4 * 147456
    if (idx >= 4 * 147456) return;
    int d = idx / 147456, r = idx % 147456;
    int e  = r & 7;
    int l  = (r >> 3) & 63;
    int nj = (r >> 9) & 3;
    int wn = (r >> 11) & 1;
    int s  = r >> 12;                  // 0..35
    int t = s >> 2, q = s & 3;
    int cout = wn * 64 + nj * 16 + (l & 15);
    int cin  = q * 32 + (l >> 4) * 8 + e;
    float v = bw[((size_t)(d * 3 + 2) * 16384 + cout * 128 + cin) * 9 + t];
    wb[idx] = f2bf(v);
}

// ---------------- init conv: cin=3, fp32 VALU, NCHW fp32 in -> NHWC bf16 out ----------------
__global__ __launch_bounds__(256) void conv_init(
    const float* __restrict__ in,    // [16][3][112][112]
    const float* __restrict__ wgt,   // [128][3][3][3]
    const float* __restrict__ bias,  // [128]
    u16* __restrict__ outp)          // [16][12544][128] bf16
{
    const int tile = blockIdx.x;          // 0..48 (16x16 tiles)
    const int cg   = blockIdx.y;          // 0..3  (32 couts)
    const int n    = blockIdx.z;
    const int h0 = (tile / 7) * 16, w0 = (tile % 7) * 16;
    const int tid = threadIdx.x;
    const int sid = tid & 63, wv = tid >> 6;
    const int tx = sid & 7, ty = sid >> 3;

    __shared__ float s_in[3][18][18];
    __shared__ float s_w[3][9][32];

    float acc[2][2][8];
    #pragma unroll
    for (int a = 0; a < 2; a++)
        #pragma unroll
        for (int b = 0; b < 2; b++)
            #pragma unroll
            for (int c = 0; c < 8; c++) acc[a][b][c] = 0.f;

    const float* in_n = in + (size_t)n * 3 * HW;
    const int cbase = cg * 32;

    for (int e = tid; e < 3 * 324; e += 256) {
        int ck = e / 324, p = e % 324;
        int y = p / 18, x = p % 18;
        int gh = h0 + y - 1, gw = w0 + x - 1;
        float v = 0.f;
        if ((unsigned)gh < 112u && (unsigned)gw < 112u)
            v = in_n[(size_t)ck * HW + gh * 112 + gw];
        s_in[ck][y][x] = v;
    }
    for (int e = tid; e < 3 * 9 * 32; e += 256) {
        int co = e / 27, r = e % 27;
        int ck = r / 9, kidx = r % 9;
        s_w[ck][kidx][co] = wgt[((size_t)(cbase + co) * 3 + ck) * 9 + kidx];
    }
    __syncthreads();

    #pragma unroll
    for (int ck = 0; ck < 3; ck++) {
        float rowv[4][4];
        #pragma unroll
        for (int r = 0; r < 4; r++) {
            float2 a  = *(const float2*)&s_in[ck][ty * 2 + r][tx * 2];
            float2 b2 = *(const float2*)&s_in[ck][ty * 2 + r][tx * 2 + 2];
            rowv[r][0] = a.x; rowv[r][1] = a.y;
            rowv[r][2] = b2.x; rowv[r][3] = b2.y;
        }
        #pragma unroll
        for (int kh = 0; kh < 3; kh++)
            #pragma unroll
            for (int kw = 0; kw < 3; kw++) {
                float i00 = rowv[kh][kw],     i01 = rowv[kh][kw + 1];
                float i10 = rowv[kh + 1][kw], i11 = rowv[kh + 1][kw + 1];
                const float* wp = &s_w[ck][kh * 3 + kw][wv * 8];
                #pragma unroll
                for (int co = 0; co < 8; co++) {
                    float wval = wp[co];
                    acc[0][0][co] += i00 * wval;
                    acc[0][1][co] += i01 * wval;
                    acc[1][0][co] += i10 * wval;
                    acc[1][1][co] += i11 * wval;
                }
            }
    }

    float bv[8];
    #pragma unroll
    for (int co = 0; co < 8; co++) bv[co] = bias[cbase + wv * 8 + co];
    #pragma unroll
    for (int dy = 0; dy < 2; dy++)
        #pragma unroll
        for (int dx = 0; dx < 2; dx++) {
            ushort8 pk;
            #pragma unroll
            for (int co = 0; co < 8; co++)
                pk[co] = f2bf(acc[dy][dx][co] + bv[co]);   // no relu on init
            int h = h0 + ty * 2 + dy, w = w0 + tx * 2 + dx;
            *(ushort8*)(outp + (((size_t)n * HW + h * 112 + w) << 7) + cbase + wv * 8) = pk;
        }
}

// ---------------- MFMA implicit-GEMM 3x3 conv, 128->128, bf16 NHWC ----------------
// Block: 256 thr (4 waves), tile M=128 pixels (8 rows x 16 cols), N=128 couts.
// Wave: 64x64. K-loop: 36 steps (tap-major, 4 cin-chunks of 32), NO barriers:
// A from LDS (staged once), B fragments direct global->reg (coalesced 1KB,
// L2-hot), depth-2 register double-buffer.
#define IN_S 136        // LDS elems per pixel (128 + 8 pad) -> 272B stride, 16B-aligned

template<bool STORE>
__global__ __launch_bounds__(256, 3) void conv_mfma(
    const u16* __restrict__ in,     // [16][12544][128] bf16
    const u16* __restrict__ wb,     // [36][2][4][64][8] bf16 fragment-major
    const float* __restrict__ bias, // [128]
    u16* __restrict__ outp,         // [16][12544][128] bf16 (unused if !STORE)
    float* __restrict__ partial)    // [16][98][128] f32 per-block pooled sums
{
    __shared__ u16 s_in[180 * IN_S];        // 48,960 B
    __shared__ float s_pool[2][128];        //  1,024 B

    const int tile = blockIdx.x;            // 0..97
    const int n    = blockIdx.y;
    const int h0 = (tile / 7) * 8, w0 = (tile % 7) * 16;
    const int tid = threadIdx.x, lane = tid & 63;
    const int wid = tid >> 6, wm = wid >> 1, wn = wid & 1;
    const int l15 = lane & 15, l4 = lane >> 4;

    // per-wave fragment base: wb + wn*2048 + lane*8 ; step stride 4096, nj stride 512
    const u16* wp = wb + (wn << 11) + (lane << 3);

    // preload steps 0,1 B-fragments (overlaps A staging below)
    uint4 b0[4], b1[4];
    #pragma unroll
    for (int nj = 0; nj < 4; ++nj) b0[nj] = *(const uint4*)(wp + (nj << 9));
    #pragma unroll
    for (int nj = 0; nj < 4; ++nj) b1[nj] = *(const uint4*)(wp + 4096 + (nj << 9));

    // ---- stage input patch 10x18 pixels x 128 cin (halo, zero-padded) ----
    const u16* in_n = in + ((size_t)n * HW << 7);
    for (int e = tid; e < 2880; e += 256) {
        int pp = e >> 4, c8 = (e & 15) << 3;
        int hh = pp / 18, ww = pp - hh * 18;
        int gh = h0 + hh - 1, gw = w0 + ww - 1;
        uint4 v = make_uint4(0, 0, 0, 0);
        if ((unsigned)gh < 112u && (unsigned)gw < 112u)
            v = *(const uint4*)(in_n + ((size_t)(gh * 112 + gw) << 7) + c8);
        *(uint4*)(s_in + pp * IN_S + c8) = v;
    }

    f32x4 acc[4][4];
    #pragma unroll
    for (int i = 0; i < 4; ++i)
        #pragma unroll
        for (int j = 0; j < 4; ++j)
            #pragma unroll
            for (int e = 0; e < 4; ++e) acc[i][j][e] = 0.f;

    int a_base[4];
    #pragma unroll
    for (int fi = 0; fi < 4; ++fi) a_base[fi] = (wm * 4 + fi) * 18 + l15;

    __syncthreads();    // s_in ready; the ONLY barrier before the epilogue

    #pragma unroll
    for (int s2 = 0; s2 < 18; ++s2) {
        // ---------- even step s = 2*s2 : consume b0, prefetch s+2 ----------
        {
            const int s = 2 * s2;
            const int t = s >> 2, q = s & 3;
            const int kh = t / 3, kw = t - kh * 3;
            const int aoff = kh * 18 + kw;

            uint4 bc[4];
            #pragma unroll
            for (int nj = 0; nj < 4; ++nj) bc[nj] = b0[nj];
            {   // prefetch (SSA: loads issue before/under the MFMAs)
                int sp = s + 2; if (sp >= 36) sp -= 36;
                const u16* wsp = wp + sp * 4096;
                #pragma unroll
                for (int nj = 0; nj < 4; ++nj)
                    b0[nj] = *(const uint4*)(wsp + (nj << 9));
            }
            bf16x8 a[4];
            #pragma unroll
            for (int fi = 0; fi < 4; ++fi) {
                const u16* p = s_in + (a_base[fi] + aoff) * IN_S + (q << 5) + (l4 << 3);
                a[fi] = __builtin_bit_cast(bf16x8, *(const short8*)p);
            }
            #pragma unroll
            for (int fi = 0; fi < 4; ++fi)
                #pragma unroll
                for (int nj = 0; nj < 4; ++nj)
                    acc[fi][nj] = __builtin_amdgcn_mfma_f32_16x16x32_bf16(
                        a[fi], __builtin_bit_cast(bf16x8, bc[nj]), acc[fi][nj], 0, 0, 0);
        }
        // ---------- odd step s = 2*s2+1 : consume b1, prefetch s+2 ----------
        {
            const int s = 2 * s2 + 1;
            const int t = s >> 2, q = s & 3;
            const int kh = t / 3, kw = t - kh * 3;
            const int aoff = kh * 18 + kw;

            uint4 bc[4];
            #pragma unroll
            for (int nj = 0; nj < 4; ++nj) bc[nj] = b1[nj];
            {
                int sp = s + 2; if (sp >= 36) sp -= 36;
                const u16* wsp = wp + sp * 4096;
                #pragma unroll
                for (int nj = 0; nj < 4; ++nj)
                    b1[nj] = *(const uint4*)(wsp + (nj << 9));
            }
            bf16x8 a[4];
            #pragma unroll
            for (int fi = 0; fi < 4; ++fi) {
                const u16* p = s_in + (a_base[fi] + aoff) * IN_S + (q << 5) + (l4 << 3);
                a[fi] = __builtin_bit_cast(bf16x8, *(const short8*)p);
            }
            #pragma unroll
            for (int fi = 0; fi < 4; ++fi)
                #pragma unroll
                for (int nj = 0; nj < 4; ++nj)
                    acc[fi][nj] = __builtin_amdgcn_mfma_f32_16x16x32_bf16(
                        a[fi], __builtin_bit_cast(bf16x8, bc[nj]), acc[fi][nj], 0, 0, 0);
        }
    }

    // ---- epilogue: bias + relu, optional bf16 NHWC stores, fused pooling ----
    // D layout: col = lane&15 (cout), row = l4*4 + reg (pixel-within-16)
    float bv[4], ps[4];
    #pragma unroll
    for (int nj = 0; nj < 4; ++nj) { bv[nj] = bias[wn * 64 + nj * 16 + l15]; ps[nj] = 0.f; }
    u16* out_n = outp + ((size_t)n * HW << 7);
    #pragma unroll
    for (int fi = 0; fi < 4; ++fi) {
        int h = h0 + wm * 4 + fi;
        #pragma unroll
        for (int j = 0; j < 4; ++j) {
            int w = w0 + (l4 << 2) + j;
            u16* pr = out_n + ((size_t)(h * 112 + w) << 7);
            #pragma unroll
            for (int nj = 0; nj < 4; ++nj) {
                float v = fmaxf(acc[fi][nj][j] + bv[nj], 0.f);
                ps[nj] += v;
                if (STORE) pr[wn * 64 + nj * 16 + l15] = f2bf(v);
            }
        }
    }
    // reduce pooled partial across the 4 l4 groups (same cout)
    #pragma unroll
    for (int nj = 0; nj < 4; ++nj) {
        ps[nj] += __shfl_xor(ps[nj], 16, 64);
        ps[nj] += __shfl_xor(ps[nj], 32, 64);
    }
    if (l4 == 0) {
        #pragma unroll
        for (int nj = 0; nj < 4; ++nj)
            s_pool[wm][wn * 64 + nj * 16 + l15] = ps[nj];
    }
    __syncthreads();
    if (tid < 128)
        partial[((size_t)n * NTILE + tile) * 128 + tid] = s_pool[0][tid] + s_pool[1][tid];
}

// ---------------- per-(depth,sample): reduce partials + 100 dot-128 ----------------
__global__ __launch_bounds__(128) void logits_k(
    const float* __restrict__ partial,  // [4][16][98][128]
    const float* __restrict__ cw,       // [4][100][128]
    const float* __restrict__ cb,       // [4][100]
    float* __restrict__ lg)             // [4][16][100]
{
    const int i = blockIdx.x, n = blockIdx.y;
    const int tid = threadIdx.x;
    __shared__ float pool[128];
    const float* pp = partial + ((size_t)(i * NB + n) * NTILE) * 128;
    float s = 0.f;
    for (int t = 0; t < NTILE; ++t) s += pp[t * 128 + tid];
    pool[tid] = s * (1.f / HW);
    __syncthreads();
    if (tid < NCLS) {
        const float* wp = cw + ((size_t)i * NCLS + tid) * CCH;
        float a = cb[i * NCLS + tid];
        #pragma unroll
        for (int c = 0; c < CCH; c += 4) {
            float4 w4 = *(const float4*)(wp + c);
            a += pool[c] * w4.x + pool[c + 1] * w4.y
               + pool[c + 2] * w4.z + pool[c + 3] * w4.w;
        }
        lg[(i * NB + n) * NCLS + tid] = a;
    }
}

// ---------------- early-exit selection ----------------
__global__ __launch_bounds__(256) void select_k(
    const float* __restrict__ lg,   // [4][16][100]
    float* __restrict__ out)        // [16][100]
{
    __shared__ float slg[4 * NB * NCLS];
    __shared__ int chosen[NB];
    const int tid = threadIdx.x;
    for (int e = tid; e < 4 * NB * NCLS; e += 256) slg[e] = lg[e];
    __syncthreads();
    if (tid < NB) {
        int n = tid, ch = 3;
        for (int i = 0; i < 3; i++) {
            const float* row = &slg[(i * NB + n) * NCLS];
            float m = -1e30f;
            for (int j = 0; j < NCLS; j++) m = fmaxf(m, row[j]);
            float se = 0.f;
            for (int j = 0; j < NCLS; j++) se += expf(row[j] - m);
            if (1.f / se >= 0.9f) { ch = i; break; }
        }
        chosen[n] = ch;
    }
    __syncthreads();
    for (int e = tid; e < NB * NCLS; e += 256) {
        int n = e / NCLS, j = e % NCLS;
        out[e] = slg[(chosen[n] * NB + n) * NCLS + j];
    }
}

extern "C" void kernel_launch(void* const* d_in, const int* in_sizes, int n_in,
                              void* d_out, int out_size, void* d_ws, size_t ws_size,
                              hipStream_t stream) {
    const float* x       = (const float*)d_in[0];
    const float* init_w  = (const float*)d_in[1];
    const float* init_b  = (const float*)d_in[2];
    const float* block_w = (const float*)d_in[3];
    const float* block_b = (const float*)d_in[4];
    const float* cls_w   = (const float*)d_in[5];
    const float* cls_b   = (const float*)d_in[6];
    float* out = (float*)d_out;

    char* ws = (char*)d_ws;
    u16* fA        = (u16*)ws;                      // 51,380,224 B
    u16* fB        = (u16*)(ws + 51380224);         // 51,380,224 B
    u16* wb        = (u16*)(ws + 102760448);        //  1,179,648 B
    float* partial = (float*)(ws + 103940096);      // 4*16*98*128*4 = 3,211,264 B
    float* lgbuf   = (float*)(ws + 107151360);      // 4*16*100*4 = 25,600 B

    convert_w<<<2304, 256, 0, stream>>>(block_w, wb);
    conv_init<<<dim3(49, 4, NB), 256, 0, stream>>>(
        x, init_w + 2 * 128 * 27, init_b + 2 * 128, fA);

    u16* cur = fA;
    u16* nxt = fB;
    for (int i = 0; i < 4; ++i) {
        if (i < 3)
            conv_mfma<true><<<dim3(NTILE, NB), 256, 0, stream>>>(
                cur, wb + (size_t)i * 147456, block_b + (i * 3 + 2) * 128, nxt,
                partial + (size_t)i * NB * NTILE * 128);
        else
            conv_mfma<false><<<dim3(NTILE, NB), 256, 0, stream>>>(
                cur, wb + (size_t)i * 147456, block_b + (i * 3 + 2) * 128, nxt,
                partial + (size_t)i * NB * NTILE * 128);
        u16* t = cur; cur = nxt; nxt = t;
    }

    logits_k<<<dim3(4, NB), 128, 0, stream>>>(partial, cls_w, cls_b, lgbuf);
    select_k<<<1, 256, 0, stream>>>(lgbuf, out);
}

// Round 8
// 426.105 us; speedup vs baseline: 1.2224x; 1.2224x over previous
//
#include <hip/hip_runtime.h>
#include <hip/hip_bf16.h>

// MSDNet on MI355X. Only scale 2's chain matters (scales 0/1 dead), and
// final_logits == logits at depth 3.
// conv_mfma v3: 2-wave blocks, wave-tile 128px x 64co (0.023 LDS-B/FLOP ->
// MFMA-bound), weights via global_load_lds into per-wave TRIPLE-buffered
// swizzled LDS (each wave stages & reads only its own half -> ZERO K-loop
// barriers), counted vmcnt(4) fences. Fused f32 pooling; layer 3 storeless.

typedef unsigned int uint;
typedef unsigned short u16;
typedef __bf16 bf16x8 __attribute__((ext_vector_type(8)));
typedef short short8 __attribute__((ext_vector_type(8)));
typedef unsigned short ushort8 __attribute__((ext_vector_type(8)));
typedef float f32x4 __attribute__((ext_vector_type(4)));

#define NB   16
#define CCH  128
#define NCLS 100
#define HW   12544      // 112*112
#define NTILE 98        // 14 h-tiles x 7 w-tiles per image

__device__ __forceinline__ u16 f2bf(float f) {
    uint u = __float_as_uint(f);
    return (u16)((u + 0x7fffu + ((u >> 16) & 1u)) >> 16);
}

__device__ __forceinline__ void gload16(const u16* g, u16* l) {
    __builtin_amdgcn_global_load_lds(
        (const __attribute__((address_space(1))) uint*)g,
        (__attribute__((address_space(3))) uint*)l, 16, 0, 0);
}

// ---------------- weight transpose+convert: block_w[d][2][co][ci][kh][kw] f32
// -> wb[d][tap][co][ci] bf16 ----------------
__global__ __launch_bounds__(256) void convert_w(
    const float* __restrict__ bw, u16* __restrict__ wb)
{
    int idx = blockIdx.x * 256 + threadIdx.x;        // 4*9*128*128
    if (idx >= 4 * 9 * 16384) return;
    int d = idx / 147456, r = idx % 147456;
    int t = r / 16384, r2 = r & 16383;
    int co = r2 >> 7, ci = r2 & 127;
    float v = bw[((size_t)(d * 3 + 2) * 16384 + co * 128 + ci) * 9 + t];
    wb[idx] = f2bf(v);
}

// ---------------- init conv: cin=3, fp32 VALU, NCHW fp32 in -> NHWC bf16 out ----------------
__global__ __launch_bounds__(256) void conv_init(
    const float* __restrict__ in,    // [16][3][112][112]
    const float* __restrict__ wgt,   // [128][3][3][3]
    const float* __restrict__ bias,  // [128]
    u16* __restrict__ outp)          // [16][12544][128] bf16
{
    const int tile = blockIdx.x;          // 0..48 (16x16 tiles)
    const int cg   = blockIdx.y;          // 0..3  (32 couts)
    const int n    = blockIdx.z;
    const int h0 = (tile / 7) * 16, w0 = (tile % 7) * 16;
    const int tid = threadIdx.x;
    const int sid = tid & 63, wv = tid >> 6;
    const int tx = sid & 7, ty = sid >> 3;

    __shared__ float s_in[3][18][18];
    __shared__ float s_w[3][9][32];

    float acc[2][2][8];
    #pragma unroll
    for (int a = 0; a < 2; a++)
        #pragma unroll
        for (int b = 0; b < 2; b++)
            #pragma unroll
            for (int c = 0; c < 8; c++) acc[a][b][c] = 0.f;

    const float* in_n = in + (size_t)n * 3 * HW;
    const int cbase = cg * 32;

    for (int e = tid; e < 3 * 324; e += 256) {
        int ck = e / 324, p = e % 324;
        int y = p / 18, x = p % 18;
        int gh = h0 + y - 1, gw = w0 + x - 1;
        float v = 0.f;
        if ((unsigned)gh < 112u && (unsigned)gw < 112u)
            v = in_n[(size_t)ck * HW + gh * 112 + gw];
        s_in[ck][y][x] = v;
    }
    for (int e = tid; e < 3 * 9 * 32; e += 256) {
        int co = e / 27, r = e % 27;
        int ck = r / 9, kidx = r % 9;
        s_w[ck][kidx][co] = wgt[((size_t)(cbase + co) * 3 + ck) * 9 + kidx];
    }
    __syncthreads();

    #pragma unroll
    for (int ck = 0; ck < 3; ck++) {
        float rowv[4][4];
        #pragma unroll
        for (int r = 0; r < 4; r++) {
            float2 a  = *(const float2*)&s_in[ck][ty * 2 + r][tx * 2];
            float2 b2 = *(const float2*)&s_in[ck][ty * 2 + r][tx * 2 + 2];
            rowv[r][0] = a.x; rowv[r][1] = a.y;
            rowv[r][2] = b2.x; rowv[r][3] = b2.y;
        }
        #pragma unroll
        for (int kh = 0; kh < 3; kh++)
            #pragma unroll
            for (int kw = 0; kw < 3; kw++) {
                float i00 = rowv[kh][kw],     i01 = rowv[kh][kw + 1];
                float i10 = rowv[kh + 1][kw], i11 = rowv[kh + 1][kw + 1];
                const float* wp = &s_w[ck][kh * 3 + kw][wv * 8];
                #pragma unroll
                for (int co = 0; co < 8; co++) {
                    float wval = wp[co];
                    acc[0][0][co] += i00 * wval;
                    acc[0][1][co] += i01 * wval;
                    acc[1][0][co] += i10 * wval;
                    acc[1][1][co] += i11 * wval;
                }
            }
    }

    float bv[8];
    #pragma unroll
    for (int co = 0; co < 8; co++) bv[co] = bias[cbase + wv * 8 + co];
    #pragma unroll
    for (int dy = 0; dy < 2; dy++)
        #pragma unroll
        for (int dx = 0; dx < 2; dx++) {
            ushort8 pk;
            #pragma unroll
            for (int co = 0; co < 8; co++)
                pk[co] = f2bf(acc[dy][dx][co] + bv[co]);   // no relu on init
            int h = h0 + ty * 2 + dy, w = w0 + tx * 2 + dx;
            *(ushort8*)(outp + (((size_t)n * HW + h * 112 + w) << 7) + cbase + wv * 8) = pk;
        }
}

// ---------------- MFMA implicit-GEMM 3x3 conv, 128->128, bf16 NHWC ----------------
// Block: 128 thr (2 waves), tile M=128 px (8 rows x 16 cols), N=128 couts.
// Wave w owns couts w*64..+63 for ALL 128 px: acc[8][4], 8 A + 4 B ds_reads,
// 32 MFMA per K-step (0.023 LDS-B/FLOP). Weights: per-wave global_load_lds
// into s_w triple-buffer; LDS pos (co',g) holds source granule g^((co'>>1)&3)
// (2-way-free banks on read). No barriers in the K-loop.
#define IN_S 136        // LDS elems per pixel (128 + 8 pad) -> 272B stride

template<bool STORE>
__global__ __launch_bounds__(128, 2) void conv_mfma(
    const u16* __restrict__ in,     // [16][12544][128] bf16
    const u16* __restrict__ wb,     // [9][128][128] bf16 (tap, cout, cin)
    const float* __restrict__ bias, // [128]
    u16* __restrict__ outp,         // [16][12544][128] bf16 (unused if !STORE)
    float* __restrict__ partial)    // [16][98][128] f32 per-block pooled sums
{
    __shared__ u16 s_in[180 * IN_S];        // 48,960 B
    __shared__ u16 s_w[3 * 2 * 2048];       // 24,576 B [buf][wave][2048]
    __shared__ float s_pool[128];

    const int tile = blockIdx.x;            // 0..97
    const int n    = blockIdx.y;
    const int h0 = (tile / 7) * 8, w0 = (tile % 7) * 16;
    const int tid = threadIdx.x, lane = tid & 63;
    const int w = tid >> 6;                 // wave id = cout half
    const int l15 = lane & 15, l4 = lane >> 4;

    // weight DMA: lane l -> LDS (co' = i*16 + (l>>2), gpos = l&3);
    // source granule c2 = gpos ^ ((co'>>1)&3) = (l&3) ^ ((l>>3)&3)
    const int co_g = w * 64 + (lane >> 2);
    const int c2e  = ((lane & 3) ^ ((lane >> 3) & 3)) << 3;
    const u16* wsrc0 = wb + co_g * 128 + c2e;   // + i*2048 + t*16384 + q*32
    u16* ldsw = s_w + w * 2048;                 // + buf*4096 + i*512

    // ---- prologue: issue W for steps 0 (buf0) and 1 (buf1) ----
    #pragma unroll
    for (int i = 0; i < 4; ++i)
        gload16(wsrc0 + (i << 11), ldsw + (i << 9));                 // s=0: t0,q0
    #pragma unroll
    for (int i = 0; i < 4; ++i)
        gload16(wsrc0 + 32 + (i << 11), ldsw + 4096 + (i << 9));     // s=1: t0,q1

    // ---- stage input patch 10x18 pixels x 128 cin (halo, zero-padded) ----
    const u16* in_n = in + ((size_t)n * HW << 7);
    for (int e = tid; e < 2880; e += 128) {
        int pp = e >> 4, c8 = (e & 15) << 3;
        int hh = pp / 18, ww = pp - hh * 18;
        int gh = h0 + hh - 1, gw = w0 + ww - 1;
        uint4 v = make_uint4(0, 0, 0, 0);
        if ((unsigned)gh < 112u && (unsigned)gw < 112u)
            v = *(const uint4*)(in_n + ((size_t)(gh * 112 + gw) << 7) + c8);
        *(uint4*)(s_in + pp * IN_S + c8) = v;
    }

    f32x4 acc[8][4];
    #pragma unroll
    for (int i = 0; i < 8; ++i)
        #pragma unroll
        for (int j = 0; j < 4; ++j)
            #pragma unroll
            for (int e = 0; e < 4; ++e) acc[i][j][e] = 0.f;

    const int pA = l15 * IN_S + (l4 << 3);
    const int pB = w * 2048 + l15 * 32 + ((l4 ^ ((l15 >> 1) & 3)) << 3);

    __syncthreads();    // s_in ready; drains vmcnt -> W(0),W(1) in LDS

    #pragma unroll
    for (int s = 0; s < 36; ++s) {
        const int t = s >> 2, q = s & 3;
        const int kh = t / 3, kw = t - kh * 3;

        // W(s) ready: <=4 outstanding leaves only batch(s+1)
        asm volatile("s_waitcnt vmcnt(4)" ::: "memory");

        bf16x8 a[8], b[4];
        #pragma unroll
        for (int fi = 0; fi < 8; ++fi) {
            const u16* p = s_in + pA + ((fi + kh) * 18 + kw) * IN_S + (q << 5);
            a[fi] = __builtin_bit_cast(bf16x8, *(const short8*)p);
        }
        const u16* wbuf = s_w + (s % 3) * 4096 + pB;
        #pragma unroll
        for (int nj = 0; nj < 4; ++nj)
            b[nj] = __builtin_bit_cast(bf16x8, *(const short8*)(wbuf + (nj << 9)));

        // issue W(s+2) into buf[(s+2)%3] (its last reads were step s-1)
        if (s < 34) {
            const int sp = s + 2;
            const u16* src = wsrc0 + (sp >> 2) * 16384 + ((sp & 3) << 5);
            u16* dst = ldsw + ((sp % 3) << 12);
            #pragma unroll
            for (int i = 0; i < 4; ++i) gload16(src + (i << 11), dst + (i << 9));
        }

        #pragma unroll
        for (int fi = 0; fi < 8; ++fi)
            #pragma unroll
            for (int nj = 0; nj < 4; ++nj)
                acc[fi][nj] = __builtin_amdgcn_mfma_f32_16x16x32_bf16(
                    a[fi], b[nj], acc[fi][nj], 0, 0, 0);
    }

    // ---- epilogue: bias + relu, optional stores, fused pooling ----
    // D layout: col = l15 (cout), row = l4*4 + j (pixel col in the fi-row)
    float bv[4], ps[4];
    #pragma unroll
    for (int nj = 0; nj < 4; ++nj) { bv[nj] = bias[w * 64 + nj * 16 + l15]; ps[nj] = 0.f; }
    u16* out_n = outp + ((size_t)n * HW << 7);
    #pragma unroll
    for (int fi = 0; fi < 8; ++fi) {
        int h = h0 + fi;
        #pragma unroll
        for (int j = 0; j < 4; ++j) {
            int wpx = w0 + (l4 << 2) + j;
            u16* pr = out_n + ((size_t)(h * 112 + wpx) << 7);
            #pragma unroll
            for (int nj = 0; nj < 4; ++nj) {
                float v = fmaxf(acc[fi][nj][j] + bv[nj], 0.f);
                ps[nj] += v;
                if (STORE) pr[w * 64 + nj * 16 + l15] = f2bf(v);
            }
        }
    }
    #pragma unroll
    for (int nj = 0; nj < 4; ++nj) {
        ps[nj] += __shfl_xor(ps[nj], 16, 64);
        ps[nj] += __shfl_xor(ps[nj], 32, 64);
    }
    if (l4 == 0) {
        #pragma unroll
        for (int nj = 0; nj < 4; ++nj)
            s_pool[w * 64 + nj * 16 + l15] = ps[nj];
    }
    __syncthreads();
    partial[((size_t)n * NTILE + tile) * 128 + tid] = s_pool[tid];
}

// ---------------- per-(depth,sample): reduce partials + 100 dot-128 ----------------
__global__ __launch_bounds__(128) void logits_k(
    const float* __restrict__ partial,  // [4][16][98][128]
    const float* __restrict__ cw,       // [4][100][128]
    const float* __restrict__ cb,       // [4][100]
    float* __restrict__ lg)             // [4][16][100]
{
    const int i = blockIdx.x, n = blockIdx.y;
    const int tid = threadIdx.x;
    __shared__ float pool[128];
    const float* pp = partial + ((size_t)(i * NB + n) * NTILE) * 128;
    float s = 0.f;
    for (int t = 0; t < NTILE; ++t) s += pp[t * 128 + tid];
    pool[tid] = s * (1.f / HW);
    __syncthreads();
    if (tid < NCLS) {
        const float* wp = cw + ((size_t)i * NCLS + tid) * CCH;
        float a = cb[i * NCLS + tid];
        #pragma unroll
        for (int c = 0; c < CCH; c += 4) {
            float4 w4 = *(const float4*)(wp + c);
            a += pool[c] * w4.x + pool[c + 1] * w4.y
               + pool[c + 2] * w4.z + pool[c + 3] * w4.w;
        }
        lg[(i * NB + n) * NCLS + tid] = a;
    }
}

// ---------------- early-exit selection ----------------
__global__ __launch_bounds__(256) void select_k(
    const float* __restrict__ lg,   // [4][16][100]
    float* __restrict__ out)        // [16][100]
{
    __shared__ float slg[4 * NB * NCLS];
    __shared__ int chosen[NB];
    const int tid = threadIdx.x;
    for (int e = tid; e < 4 * NB * NCLS; e += 256) slg[e] = lg[e];
    __syncthreads();
    if (tid < NB) {
        int n = tid, ch = 3;
        for (int i = 0; i < 3; i++) {
            const float* row = &slg[(i * NB + n) * NCLS];
            float m = -1e30f;
            for (int j = 0; j < NCLS; j++) m = fmaxf(m, row[j]);
            float se = 0.f;
            for (int j = 0; j < NCLS; j++) se += expf(row[j] - m);
            if (1.f / se >= 0.9f) { ch = i; break; }
        }
        chosen[n] = ch;
    }
    __syncthreads();
    for (int e = tid; e < NB * NCLS; e += 256) {
        int n = e / NCLS, j = e % NCLS;
        out[e] = slg[(chosen[n] * NB + n) * NCLS + j];
    }
}

extern "C" void kernel_launch(void* const* d_in, const int* in_sizes, int n_in,
                              void* d_out, int out_size, void* d_ws, size_t ws_size,
                              hipStream_t stream) {
    const float* x       = (const float*)d_in[0];
    const float* init_w  = (const float*)d_in[1];
    const float* init_b  = (const float*)d_in[2];
    const float* block_w = (const float*)d_in[3];
    const float* block_b = (const float*)d_in[4];
    const float* cls_w   = (const float*)d_in[5];
    const float* cls_b   = (const float*)d_in[6];
    float* out = (float*)d_out;

    char* ws = (char*)d_ws;
    u16* fA        = (u16*)ws;                      // 51,380,224 B
    u16* fB        = (u16*)(ws + 51380224);         // 51,380,224 B
    u16* wb        = (u16*)(ws + 102760448);        //  1,179,648 B
    float* partial = (float*)(ws + 103940096);      // 4*16*98*128*4 = 3,211,264 B
    float* lgbuf   = (float*)(ws + 107151360);      // 4*16*100*4 = 25,600 B

    convert_w<<<2304, 256, 0, stream>>>(block_w, wb);
    conv_init<<<dim3(49, 4, NB), 256, 0, stream>>>(
        x, init_w + 2 * 128 * 27, init_b + 2 * 128, fA);

    u16* cur = fA;
    u16* nxt = fB;
    for (int i = 0; i < 4; ++i) {
        if (i < 3)
            conv_mfma<true><<<dim3(NTILE, NB), 128, 0, stream>>>(
                cur, wb + (size_t)i * 147456, block_b + (i * 3 + 2) * 128, nxt,
                partial + (size_t)i * NB * NTILE * 128);
        else
            conv_mfma<false><<<dim3(NTILE, NB), 128, 0, stream>>>(
                cur, wb + (size_t)i * 147456, block_b + (i * 3 + 2) * 128, nxt,
                partial + (size_t)i * NB * NTILE * 128);
        u16* t = cur; cur = nxt; nxt = t;
    }

    logits_k<<<dim3(4, NB), 128, 0, stream>>>(partial, cls_w, cls_b, lgbuf);
    select_k<<<1, 256, 0, stream>>>(lgbuf, out);
}

// Round 9
// 339.319 us; speedup vs baseline: 1.5351x; 1.2558x over previous
//
#include <hip/hip_runtime.h>
#include <hip/hip_bf16.h>

// MSDNet on MI355X. Only scale 2's chain matters (scales 0/1 dead), and
// final_logits == logits at depth 3.
// conv_mfma v4 = r6 (best, 87us/conv) + per-q A-chunk streaming:
//   q-outer/tap-inner loop, s_in holds one 32-cin chunk (14.4KB) -> LDS
//   34.9KB -> 3 blocks/CU (12 waves) instead of 2 (8 waves).
//   W pipeline unchanged from r6: depth-2 reg prefetch -> LDS dbuf ->
//   step barrier with lgkmcnt(0) only (no vmcnt drain).

typedef unsigned int uint;
typedef unsigned short u16;
typedef __bf16 bf16x8 __attribute__((ext_vector_type(8)));
typedef short short8 __attribute__((ext_vector_type(8)));
typedef unsigned short ushort8 __attribute__((ext_vector_type(8)));
typedef float f32x4 __attribute__((ext_vector_type(4)));

#define NB   16
#define CCH  128
#define NCLS 100
#define HW   12544      // 112*112
#define NTILE 98        // 14 h-tiles x 7 w-tiles per image

__device__ __forceinline__ u16 f2bf(float f) {
    uint u = __float_as_uint(f);
    return (u16)((u + 0x7fffu + ((u >> 16) & 1u)) >> 16);
}

// ---------------- weight transpose+convert: block_w[d][2][co][ci][kh][kw] f32
// -> wb[d][tap][co][ci] bf16 ----------------
__global__ __launch_bounds__(256) void convert_w(
    const float* __restrict__ bw, u16* __restrict__ wb)
{
    int idx = blockIdx.x * 256 + threadIdx.x;        // 4*9*128*128
    if (idx >= 4 * 9 * 16384) return;
    int d = idx / 147456, r = idx % 147456;
    int t = r / 16384, r2 = r & 16383;
    int co = r2 >> 7, ci = r2 & 127;
    float v = bw[((size_t)(d * 3 + 2) * 16384 + co * 128 + ci) * 9 + t];
    wb[idx] = f2bf(v);
}

// ---------------- init conv: cin=3, fp32 VALU, NCHW fp32 in -> NHWC bf16 out ----------------
__global__ __launch_bounds__(256) void conv_init(
    const float* __restrict__ in,    // [16][3][112][112]
    const float* __restrict__ wgt,   // [128][3][3][3]
    const float* __restrict__ bias,  // [128]
    u16* __restrict__ outp)          // [16][12544][128] bf16
{
    const int tile = blockIdx.x;          // 0..48 (16x16 tiles)
    const int cg   = blockIdx.y;          // 0..3  (32 couts)
    const int n    = blockIdx.z;
    const int h0 = (tile / 7) * 16, w0 = (tile % 7) * 16;
    const int tid = threadIdx.x;
    const int sid = tid & 63, wv = tid >> 6;
    const int tx = sid & 7, ty = sid >> 3;

    __shared__ float s_in[3][18][18];
    __shared__ float s_w[3][9][32];

    float acc[2][2][8];
    #pragma unroll
    for (int a = 0; a < 2; a++)
        #pragma unroll
        for (int b = 0; b < 2; b++)
            #pragma unroll
            for (int c = 0; c < 8; c++) acc[a][b][c] = 0.f;

    const float* in_n = in + (size_t)n * 3 * HW;
    const int cbase = cg * 32;

    for (int e = tid; e < 3 * 324; e += 256) {
        int ck = e / 324, p = e % 324;
        int y = p / 18, x = p % 18;
        int gh = h0 + y - 1, gw = w0 + x - 1;
        float v = 0.f;
        if ((unsigned)gh < 112u && (unsigned)gw < 112u)
            v = in_n[(size_t)ck * HW + gh * 112 + gw];
        s_in[ck][y][x] = v;
    }
    for (int e = tid; e < 3 * 9 * 32; e += 256) {
        int co = e / 27, r = e % 27;
        int ck = r / 9, kidx = r % 9;
        s_w[ck][kidx][co] = wgt[((size_t)(cbase + co) * 3 + ck) * 9 + kidx];
    }
    __syncthreads();

    #pragma unroll
    for (int ck = 0; ck < 3; ck++) {
        float rowv[4][4];
        #pragma unroll
        for (int r = 0; r < 4; r++) {
            float2 a  = *(const float2*)&s_in[ck][ty * 2 + r][tx * 2];
            float2 b2 = *(const float2*)&s_in[ck][ty * 2 + r][tx * 2 + 2];
            rowv[r][0] = a.x; rowv[r][1] = a.y;
            rowv[r][2] = b2.x; rowv[r][3] = b2.y;
        }
        #pragma unroll
        for (int kh = 0; kh < 3; kh++)
            #pragma unroll
            for (int kw = 0; kw < 3; kw++) {
                float i00 = rowv[kh][kw],     i01 = rowv[kh][kw + 1];
                float i10 = rowv[kh + 1][kw], i11 = rowv[kh + 1][kw + 1];
                const float* wp = &s_w[ck][kh * 3 + kw][wv * 8];
                #pragma unroll
                for (int co = 0; co < 8; co++) {
                    float wval = wp[co];
                    acc[0][0][co] += i00 * wval;
                    acc[0][1][co] += i01 * wval;
                    acc[1][0][co] += i10 * wval;
                    acc[1][1][co] += i11 * wval;
                }
            }
    }

    float bv[8];
    #pragma unroll
    for (int co = 0; co < 8; co++) bv[co] = bias[cbase + wv * 8 + co];
    #pragma unroll
    for (int dy = 0; dy < 2; dy++)
        #pragma unroll
        for (int dx = 0; dx < 2; dx++) {
            ushort8 pk;
            #pragma unroll
            for (int co = 0; co < 8; co++)
                pk[co] = f2bf(acc[dy][dx][co] + bv[co]);   // no relu on init
            int h = h0 + ty * 2 + dy, w = w0 + tx * 2 + dx;
            *(ushort8*)(outp + (((size_t)n * HW + h * 112 + w) << 7) + cbase + wv * 8) = pk;
        }
}

// ---------------- MFMA implicit-GEMM 3x3 conv, 128->128, bf16 NHWC ----------------
// Block: 256 thr (4 waves), tile M=128 px (8 rows x 16 cols), N=128 couts.
// Wave: 64px x 64co. Loop: q outer (4 cin-chunks), taps inner (9). Per-q A
// chunk in s_in[180][40] (14.4KB). W: depth-2 reg prefetch -> LDS dbuf ->
// step barrier without vmcnt drain (r6-proven). 3 blocks/CU.
#define AS 40           // s_in elems per px (32 + 8 pad) -> 80B stride, 16B-aligned
#define W_S 40          // s_w elems per cout (32 + 8 pad) -> 80B stride

template<bool STORE>
__global__ __launch_bounds__(256, 3) void conv_mfma(
    const u16* __restrict__ in,     // [16][12544][128] bf16
    const u16* __restrict__ wb,     // [9][128][128] bf16 (tap, cout, cin)
    const float* __restrict__ bias, // [128]
    u16* __restrict__ outp,         // [16][12544][128] bf16 (unused if !STORE)
    float* __restrict__ partial)    // [16][98][128] f32 per-block pooled sums
{
    __shared__ u16 s_in[180 * AS];          // 14,400 B (one q-chunk + halo)
    __shared__ u16 s_w[2 * 128 * W_S];      // 20,480 B
    float* s_pool = (float*)s_in;           // overlay (used after K-loop)

    const int tile = blockIdx.x;            // 0..97
    const int n    = blockIdx.y;
    const int h0 = (tile / 7) * 8, w0 = (tile % 7) * 16;
    const int tid = threadIdx.x, lane = tid & 63;
    const int wid = tid >> 6, wm = wid >> 1, wn = wid & 1;
    const int l15 = lane & 15, l4 = lane >> 4;

    const u16* in_n = in + ((size_t)n * HW << 7);

    // A-staging roles: granule g = tid + r*256 (g<720): px = g>>2, c = g&3
    // src 16B at feat[px][q*32 + c*8]; dst s_in[px*AS + c*8]
    int st_px[3], st_c8[3];
    long st_src[3];
    #pragma unroll
    for (int r = 0; r < 3; ++r) {
        int g = tid + (r << 8);
        int px = g >> 2, c8 = (g & 3) << 3;
        int hh = px / 18, ww = px - hh * 18;
        int gh = h0 + hh - 1, gw = w0 + ww - 1;
        bool inb = (g < 720) && ((unsigned)gh < 112u) && ((unsigned)gw < 112u);
        st_px[r] = (g < 720) ? px : -1;
        st_c8[r] = c8;
        st_src[r] = inb ? (((long)(gh * 112 + gw)) << 7) + c8 : -1;
    }

    // weight staging roles (r6): thread handles couts co0 and co0+64, 16B each
    const int co0 = tid >> 2, k0 = (tid & 3) << 3;

    // ---- prologue: stage A(q=0), stage W(step 0) -> buf0, preload W(1) regs ----
    #pragma unroll
    for (int r = 0; r < 3; ++r) {
        if (st_px[r] >= 0) {
            uint4 v = make_uint4(0, 0, 0, 0);
            if (st_src[r] >= 0) v = *(const uint4*)(in_n + st_src[r]);
            *(uint4*)(s_in + st_px[r] * AS + st_c8[r]) = v;
        }
    }
    *(uint4*)(s_w + co0 * W_S + k0)        = *(const uint4*)(wb + (co0 << 7) + k0);
    *(uint4*)(s_w + (co0 + 64) * W_S + k0) = *(const uint4*)(wb + ((co0 + 64) << 7) + k0);

    uint4 wcur0, wcur1, wnxt0, wnxt1;
    {   // W(step 1) = (q=0, t=1): src wb + 1*16384
        const u16* ws1 = wb + 16384;
        wcur0 = *(const uint4*)(ws1 + (co0 << 7) + k0);
        wcur1 = *(const uint4*)(ws1 + ((co0 + 64) << 7) + k0);
    }

    f32x4 acc[4][4];
    #pragma unroll
    for (int i = 0; i < 4; ++i)
        #pragma unroll
        for (int j = 0; j < 4; ++j)
            #pragma unroll
            for (int e = 0; e < 4; ++e) acc[i][j][e] = 0.f;

    int a_base[4], b_base[4];
    #pragma unroll
    for (int fi = 0; fi < 4; ++fi) a_base[fi] = (wm * 4 + fi) * 18 + l15;
    #pragma unroll
    for (int nj = 0; nj < 4; ++nj) b_base[nj] = (wn * 64 + nj * 16 + l15) * W_S + (l4 << 3);

    __syncthreads();    // A(0) + W-buf0 visible

    for (int q = 0; q < 4; ++q) {
        if (q > 0) {
            // all reads of previous phase finished at the last step barrier;
            // restage s_in with chunk q
            #pragma unroll
            for (int r = 0; r < 3; ++r) {
                if (st_px[r] >= 0) {
                    uint4 v = make_uint4(0, 0, 0, 0);
                    if (st_src[r] >= 0)
                        v = *(const uint4*)(in_n + st_src[r] + (q << 5));
                    *(uint4*)(s_in + st_px[r] * AS + st_c8[r]) = v;
                }
            }
            __syncthreads();
        }

        #pragma unroll
        for (int t = 0; t < 9; ++t) {
            const int s = q * 9 + t;            // global step; W(s) in buf[s&1]
            const int kh = t / 3, kw = t - kh * 3;

            // fragment reads
            bf16x8 a[4], b[4];
            #pragma unroll
            for (int fi = 0; fi < 4; ++fi) {
                const u16* p = s_in + (a_base[fi] + kh * 18 + kw) * AS + (l4 << 3);
                a[fi] = __builtin_bit_cast(bf16x8, *(const short8*)p);
            }
            const u16* wbuf = s_w + (s & 1) * (128 * W_S);
            #pragma unroll
            for (int nj = 0; nj < 4; ++nj)
                b[nj] = __builtin_bit_cast(bf16x8, *(const short8*)(wbuf + b_base[nj]));

            // prefetch W(s+2): tap (s+2)%9, q-chunk (s+2)/9 (wrap harmless)
            {
                int sp = s + 2; if (sp >= 36) sp -= 36;
                const u16* wsj = wb + (sp % 9) * 16384 + ((sp / 9) << 5);
                wnxt0 = *(const uint4*)(wsj + (co0 << 7) + k0);
                wnxt1 = *(const uint4*)(wsj + ((co0 + 64) << 7) + k0);
            }

            #pragma unroll
            for (int fi = 0; fi < 4; ++fi)
                #pragma unroll
                for (int nj = 0; nj < 4; ++nj)
                    acc[fi][nj] = __builtin_amdgcn_mfma_f32_16x16x32_bf16(
                        a[fi], b[nj], acc[fi][nj], 0, 0, 0);

            // ds_write W(s+1) -> buf[(s+1)&1] (counted vmcnt, not a drain)
            {
                u16* wdst = s_w + ((s + 1) & 1) * (128 * W_S);
                *(uint4*)(wdst + co0 * W_S + k0)        = wcur0;
                *(uint4*)(wdst + (co0 + 64) * W_S + k0) = wcur1;
            }
            wcur0 = wnxt0; wcur1 = wnxt1;

            // step barrier WITHOUT vmcnt drain
            asm volatile("s_waitcnt lgkmcnt(0)" ::: "memory");
            __builtin_amdgcn_s_barrier();
            __builtin_amdgcn_sched_barrier(0);
        }
    }

    // ---- epilogue: bias + relu, optional bf16 NHWC stores, fused pooling ----
    // D layout: col = lane&15 (cout), row = l4*4 + j (pixel-within-16)
    float bv[4], ps[4];
    #pragma unroll
    for (int nj = 0; nj < 4; ++nj) { bv[nj] = bias[wn * 64 + nj * 16 + l15]; ps[nj] = 0.f; }
    u16* out_n = outp + ((size_t)n * HW << 7);
    #pragma unroll
    for (int fi = 0; fi < 4; ++fi) {
        int h = h0 + wm * 4 + fi;
        #pragma unroll
        for (int j = 0; j < 4; ++j) {
            int w = w0 + (l4 << 2) + j;
            u16* pr = out_n + ((size_t)(h * 112 + w) << 7);
            #pragma unroll
            for (int nj = 0; nj < 4; ++nj) {
                float v = fmaxf(acc[fi][nj][j] + bv[nj], 0.f);
                ps[nj] += v;
                if (STORE) pr[wn * 64 + nj * 16 + l15] = f2bf(v);
            }
        }
    }
    #pragma unroll
    for (int nj = 0; nj < 4; ++nj) {
        ps[nj] += __shfl_xor(ps[nj], 16, 64);
        ps[nj] += __shfl_xor(ps[nj], 32, 64);
    }
    __syncthreads();    // all s_in reads long done; reuse as pool buffer
    if (l4 == 0) {
        #pragma unroll
        for (int nj = 0; nj < 4; ++nj)
            s_pool[wm * 128 + wn * 64 + nj * 16 + l15] = ps[nj];
    }
    __syncthreads();
    if (tid < 128)
        partial[((size_t)n * NTILE + tile) * 128 + tid] = s_pool[tid] + s_pool[128 + tid];
}

// ---------------- per-(depth,sample): reduce partials + 100 dot-128 ----------------
__global__ __launch_bounds__(128) void logits_k(
    const float* __restrict__ partial,  // [4][16][98][128]
    const float* __restrict__ cw,       // [4][100][128]
    const float* __restrict__ cb,       // [4][100]
    float* __restrict__ lg)             // [4][16][100]
{
    const int i = blockIdx.x, n = blockIdx.y;
    const int tid = threadIdx.x;
    __shared__ float pool[128];
    const float* pp = partial + ((size_t)(i * NB + n) * NTILE) * 128;
    float s = 0.f;
    for (int t = 0; t < NTILE; ++t) s += pp[t * 128 + tid];
    pool[tid] = s * (1.f / HW);
    __syncthreads();
    if (tid < NCLS) {
        const float* wp = cw + ((size_t)i * NCLS + tid) * CCH;
        float a = cb[i * NCLS + tid];
        #pragma unroll
        for (int c = 0; c < CCH; c += 4) {
            float4 w4 = *(const float4*)(wp + c);
            a += pool[c] * w4.x + pool[c + 1] * w4.y
               + pool[c + 2] * w4.z + pool[c + 3] * w4.w;
        }
        lg[(i * NB + n) * NCLS + tid] = a;
    }
}

// ---------------- early-exit selection ----------------
__global__ __launch_bounds__(256) void select_k(
    const float* __restrict__ lg,   // [4][16][100]
    float* __restrict__ out)        // [16][100]
{
    __shared__ float slg[4 * NB * NCLS];
    __shared__ int chosen[NB];
    const int tid = threadIdx.x;
    for (int e = tid; e < 4 * NB * NCLS; e += 256) slg[e] = lg[e];
    __syncthreads();
    if (tid < NB) {
        int n = tid, ch = 3;
        for (int i = 0; i < 3; i++) {
            const float* row = &slg[(i * NB + n) * NCLS];
            float m = -1e30f;
            for (int j = 0; j < NCLS; j++) m = fmaxf(m, row[j]);
            float se = 0.f;
            for (int j = 0; j < NCLS; j++) se += expf(row[j] - m);
            if (1.f / se >= 0.9f) { ch = i; break; }
        }
        chosen[n] = ch;
    }
    __syncthreads();
    for (int e = tid; e < NB * NCLS; e += 256) {
        int n = e / NCLS, j = e % NCLS;
        out[e] = slg[(chosen[n] * NB + n) * NCLS + j];
    }
}

extern "C" void kernel_launch(void* const* d_in, const int* in_sizes, int n_in,
                              void* d_out, int out_size, void* d_ws, size_t ws_size,
                              hipStream_t stream) {
    const float* x       = (const float*)d_in[0];
    const float* init_w  = (const float*)d_in[1];
    const float* init_b  = (const float*)d_in[2];
    const float* block_w = (const float*)d_in[3];
    const float* block_b = (const float*)d_in[4];
    const float* cls_w   = (const float*)d_in[5];
    const float* cls_b   = (const float*)d_in[6];
    float* out = (float*)d_out;

    char* ws = (char*)d_ws;
    u16* fA        = (u16*)ws;                      // 51,380,224 B
    u16* fB        = (u16*)(ws + 51380224);         // 51,380,224 B
    u16* wb        = (u16*)(ws + 102760448);        //  1,179,648 B
    float* partial = (float*)(ws + 103940096);      // 4*16*98*128*4 = 3,211,264 B
    float* lgbuf   = (float*)(ws + 107151360);      // 4*16*100*4 = 25,600 B

    convert_w<<<2304, 256, 0, stream>>>(block_w, wb);
    conv_init<<<dim3(49, 4, NB), 256, 0, stream>>>(
        x, init_w + 2 * 128 * 27, init_b + 2 * 128, fA);

    u16* cur = fA;
    u16* nxt = fB;
    for (int i = 0; i < 4; ++i) {
        if (i < 3)
            conv_mfma<true><<<dim3(NTILE, NB), 256, 0, stream>>>(
                cur, wb + (size_t)i * 147456, block_b + (i * 3 + 2) * 128, nxt,
                partial + (size_t)i * NB * NTILE * 128);
        else
            conv_mfma<false><<<dim3(NTILE, NB), 256, 0, stream>>>(
                cur, wb + (size_t)i * 147456, block_b + (i * 3 + 2) * 128, nxt,
                partial + (size_t)i * NB * NTILE * 128);
        u16* t = cur; cur = nxt; nxt = t;
    }

    logits_k<<<dim3(4, NB), 128, 0, stream>>>(partial, cls_w, cls_b, lgbuf);
    select_k<<<1, 256, 0, stream>>>(lgbuf, out);
}